// Round 5
// baseline (257.616 us; speedup 1.0000x reference)
//
#include <hip/hip_runtime.h>
#include <hip/hip_bf16.h>

#define NREL 5000
#define NBIN 32
#define NEDGE 200000
#define DIM 512
#define NHEAD 8

typedef __attribute__((ext_vector_type(8))) short short8;
typedef __attribute__((ext_vector_type(4))) float f32x4;
typedef unsigned short ushort_t;

#define REL_N (NREL * DIM)
#define BIN_N (NBIN * DIM)
#define WATTN_N (DIM * 3 * DIM)
#define VEC_N DIM
#define WAGGR_N (DIM * DIM)

__device__ __forceinline__ float b2f(ushort_t u) {
  unsigned int v = ((unsigned int)u) << 16;
  union { unsigned int i; float f; } c; c.i = v; return c.f;
}
__device__ __forceinline__ ushort_t f2b_rne(float f) {
  union { float f; unsigned int u; } c; c.f = f;
  unsigned int u = c.u;
  return (ushort_t)((u + 0x7FFFu + ((u >> 16) & 1u)) >> 16);
}

// ---------- dtype detection ----------
__global__ void detect_k(const ushort_t* __restrict__ emb_raw,
                         const int* __restrict__ trip_raw,
                         int* __restrict__ flags) {
  __shared__ int cnt_s, nz_s;
  if (threadIdx.x == 0) { cnt_s = 0; nz_s = 0; }
  __syncthreads();
  int plaus = 0;
  for (int i = threadIdx.x; i < 4096; i += 256) {
    ushort_t u = emb_raw[2 * i];
    int e = (u >> 7) & 0xFF;
    if (e >= 96 && e <= 159) plaus++;
  }
  atomicAdd(&cnt_s, plaus);
  int nz = 0;
  for (int i = threadIdx.x; i < 2048; i += 256) {
    if (trip_raw[2 * i + 1] != 0) nz++;
  }
  atomicAdd(&nz_s, nz);
  __syncthreads();
  if (threadIdx.x == 0) {
    flags[0] = (cnt_s >= 3900) ? 1 : 0;
    flags[1] = (nz_s == 0) ? 1 : 0;
  }
}

// ---------- canonicalize all float tensors -> bf16 (one kernel) ----------
__global__ void conv_all(const void* __restrict__ s_rel, const void* __restrict__ s_bin,
                         const void* __restrict__ s_wattn, const void* __restrict__ s_battn,
                         const void* __restrict__ s_avec, const void* __restrict__ s_waggr,
                         const void* __restrict__ s_baggr, ushort_t* __restrict__ dst,
                         const int* __restrict__ flags) {
  const int O1 = REL_N, O2 = O1 + BIN_N, O3 = O2 + WATTN_N, O4 = O3 + VEC_N,
            O5 = O4 + VEC_N, O6 = O5 + WAGGR_N, O7 = O6 + VEC_N;
  int i = blockIdx.x * 256 + threadIdx.x;
  if (i >= O7) return;
  const void* src; int j;
  if (i < O1)      { src = s_rel;   j = i; }
  else if (i < O2) { src = s_bin;   j = i - O1; }
  else if (i < O3) { src = s_wattn; j = i - O2; }
  else if (i < O4) { src = s_battn; j = i - O3; }
  else if (i < O5) { src = s_avec;  j = i - O4; }
  else if (i < O6) { src = s_waggr; j = i - O5; }
  else             { src = s_baggr; j = i - O6; }
  dst[i] = flags[0] ? ((const ushort_t*)src)[j] : f2b_rne(((const float*)src)[j]);
}

// ---------- triplets -> int32 (clamped) + head count ----------
__global__ void convt_count(const int* __restrict__ src, int* __restrict__ dst,
                            int* __restrict__ cnt, const int* __restrict__ flags) {
  int e = blockIdx.x * blockDim.x + threadIdx.x;
  if (e >= NEDGE) return;
  int h, ta, bi;
  if (flags[1]) { h = src[6 * e]; ta = src[6 * e + 2]; bi = src[6 * e + 4]; }
  else          { h = src[3 * e]; ta = src[3 * e + 1]; bi = src[3 * e + 2]; }
  h  = min(max(h, 0), NREL - 1);
  ta = min(max(ta, 0), NREL - 1);
  bi = min(max(bi, 0), NBIN - 1);
  dst[3 * e] = h; dst[3 * e + 1] = ta; dst[3 * e + 2] = bi;
  atomicAdd(&cnt[h], 1);
}

// ---------- fast single-block exclusive scan over 5000 counts ----------
__global__ __launch_bounds__(256) void scan_k(const int* __restrict__ cnt, int* __restrict__ off) {
  __shared__ int wsum[4];
  int t = threadIdx.x, l = t & 63, w = t >> 6;
  int base = t * 20;
  int vals[20];
  int s = 0;
#pragma unroll
  for (int j = 0; j < 20; ++j) {
    int v = (base + j < NREL) ? cnt[base + j] : 0;
    vals[j] = s; s += v;
  }
  int x = s;
#pragma unroll
  for (int d = 1; d < 64; d <<= 1) {
    int y = __shfl_up(x, d, 64);
    if (l >= d) x += y;
  }
  if (l == 63) wsum[w] = x;
  __syncthreads();
  int woff = 0;
  for (int k = 0; k < 4; ++k) if (k < w) woff += wsum[k];
  int thr_excl = woff + x - s;
#pragma unroll
  for (int j = 0; j < 20; ++j)
    if (base + j < NREL) off[base + j] = thr_excl + vals[j];
  if (t == 255) off[NREL] = woff + x;
}

// ---------- scatter packed (tail | bin<<16) into CSR slots ----------
__global__ void scatter_k(const int* __restrict__ trip, const int* __restrict__ off,
                          int* __restrict__ cur, unsigned int* __restrict__ etb) {
  int e = blockIdx.x * blockDim.x + threadIdx.x;
  if (e >= NEDGE) return;
  int h = trip[3 * e];
  int ta = trip[3 * e + 1];
  int bi = trip[3 * e + 2];
  int p = atomicAdd(&cur[h], 1);
  etb[off[h] + p] = (unsigned int)ta | ((unsigned int)bi << 16);
}

// ---------- fused GEMMs: z=0:P1(f32) 1:P3(f32) 2:Mw(bf16,+b_aggr) 3:P2(f32,+b_attn) ----------
__global__ __launch_bounds__(256) void gemm_all(
    const ushort_t* __restrict__ c_rel, const ushort_t* __restrict__ c_bin,
    const ushort_t* __restrict__ c_wattn, const ushort_t* __restrict__ c_battn,
    const ushort_t* __restrict__ c_waggr, const ushort_t* __restrict__ c_baggr,
    float* __restrict__ P1, float* __restrict__ P2, float* __restrict__ P3,
    ushort_t* __restrict__ Mw)
{
  int z = blockIdx.z;
  if (z == 3 && blockIdx.x > 0) return;
  const ushort_t* A = (z == 3) ? c_bin : c_rel;
  int Mrows = (z == 3) ? NBIN : NREL;
  const ushort_t* W = (z == 2) ? c_waggr : c_wattn;
  int wld = (z == 2) ? DIM : 3 * DIM;
  int woff = (z == 1) ? 2 * DIM : ((z == 3) ? DIM : 0);
  const ushort_t* bias = (z == 2) ? c_baggr : ((z == 3) ? c_battn : nullptr);
  float* OUTF = (z == 0) ? P1 : ((z == 1) ? P3 : P2);

  int l = threadIdx.x & 63;
  int wv = threadIdx.x >> 6;
  int rt = blockIdx.x * 64 + wv * 16;
  int ct = blockIdx.y * 64;
  int klo = (l >> 4) * 8;
  int rA = rt + (l & 15);
  f32x4 acc[4] = {};
  for (int kk = 0; kk < DIM; kk += 32) {
    short8 a = {};
    if (rA < Mrows)
      a = *(const short8*)(A + rA * DIM + kk + klo);
#pragma unroll
    for (int n = 0; n < 4; ++n) {
      int col = ct + n * 16 + (l & 15);
      short8 b = *(const short8*)(W + col * wld + woff + kk + klo);
      acc[n] = __builtin_amdgcn_mfma_f32_16x16x32_bf16(a, b, acc[n], 0, 0, 0);
    }
  }
  int r0 = rt + (l >> 4) * 4;
#pragma unroll
  for (int n = 0; n < 4; ++n) {
    int col = ct + n * 16 + (l & 15);
    float bv = bias ? b2f(bias[col]) : 0.0f;
#pragma unroll
    for (int j = 0; j < 4; ++j) {
      int row = r0 + j;
      if (row >= Mrows) continue;
      float v = acc[n][j] + bv;
      if (z == 2) Mw[(size_t)row * DIM + col] = f2b_rne(v);
      else        OUTF[(size_t)row * DIM + col] = v;
    }
  }
}

// ---------- aggregation: 2 waves per relation, 2 relations per block ----------
// single-pass online softmax (per head) with defer-max; barrier-free main loop
__global__ __launch_bounds__(256, 8) void aggr2_k(
    const int* __restrict__ off, const unsigned int* __restrict__ etb,
    const float* __restrict__ P1, const float* __restrict__ P2,
    const float* __restrict__ P3, const ushort_t* __restrict__ Mw,
    const ushort_t* __restrict__ avec, float* __restrict__ outf,
    ushort_t* __restrict__ outb, const int* __restrict__ flags)
{
  __shared__ __align__(16) float red[4][DIM];
  __shared__ float ms[4][NHEAD][2];   // per-wave, PER-HEAD (m, s)

  int t = threadIdx.x;
  int l = t & 63, wv = t >> 6;
  int p = wv >> 1, sub = wv & 1;
  int r = blockIdx.x * 2 + p;
  int off0 = off[r];
  int nE = off[r + 1] - off0;
  int half = nE >> 1;
  int start = sub ? half : 0;
  int cnt = sub ? (nE - half) : half;

  int hd1 = l >> 3;                 // head owned by this lane group
  int ob = hd1 * 64 + (l & 7) * 8;  // dim block for pass1 dot

  float p1v[8], avv[8];
#pragma unroll
  for (int j = 0; j < 8; ++j) {
    p1v[j] = P1[r * DIM + ob + j];
    avv[j] = b2f(avec[ob + j]);
  }
  float acc[8] = {};
  float m = -INFINITY, s = 0.0f;    // per-lane == per-head state

  for (int ck = 0; ck < cnt; ck += 64) {
    int ne = min(64, cnt - ck);
    unsigned int tbreg = 0;
    if (l < ne) tbreg = etb[off0 + start + ck + l];
    for (int i = 0; i < ne; ++i) {
      unsigned int tb = __shfl((int)tbreg, i);
      int tail = tb & 0xFFFF;
      int bin = tb >> 16;
      const float4* p2p = (const float4*)(P2 + bin * DIM + ob);
      const float4* p3p = (const float4*)(P3 + (size_t)tail * DIM + ob);
      float4 p2a = p2p[0], p2b = p2p[1];
      float4 p3a = p3p[0], p3b = p3p[1];
      short8 mv = *(const short8*)(Mw + (size_t)tail * DIM + 8 * l);
      float part = 0.0f, z;
      z = p1v[0] + p2a.x + p3a.x; z = z > 0.f ? z : 0.2f * z; part += z * avv[0];
      z = p1v[1] + p2a.y + p3a.y; z = z > 0.f ? z : 0.2f * z; part += z * avv[1];
      z = p1v[2] + p2a.z + p3a.z; z = z > 0.f ? z : 0.2f * z; part += z * avv[2];
      z = p1v[3] + p2a.w + p3a.w; z = z > 0.f ? z : 0.2f * z; part += z * avv[3];
      z = p1v[4] + p2b.x + p3b.x; z = z > 0.f ? z : 0.2f * z; part += z * avv[4];
      z = p1v[5] + p2b.y + p3b.y; z = z > 0.f ? z : 0.2f * z; part += z * avv[5];
      z = p1v[6] + p2b.z + p3b.z; z = z > 0.f ? z : 0.2f * z; part += z * avv[6];
      z = p1v[7] + p2b.w + p3b.w; z = z > 0.f ? z : 0.2f * z; part += z * avv[7];
      part += __shfl_xor(part, 1);
      part += __shfl_xor(part, 2);
      part += __shfl_xor(part, 4);   // per-head logit (uniform within 8-lane group)
      if (part > m + 8.0f) {         // defer-max rescale (group-uniform branch)
        float f = __expf(m - part);  // first edge: exp(-inf)=0
        s *= f;
#pragma unroll
        for (int j = 0; j < 8; ++j) acc[j] *= f;
        m = part;
      }
      float ev = __expf(part - m);
      s += ev;
#pragma unroll
      for (int j = 0; j < 8; ++j) acc[j] += ev * b2f((ushort_t)mv[j]);
    }
  }

  // ---- merge the two half-relation waves (one barrier) ----
#pragma unroll
  for (int j = 0; j < 8; ++j) red[wv][8 * l + j] = acc[j];
  if ((l & 7) == 0) { ms[wv][hd1][0] = m; ms[wv][hd1][1] = s; }
  __syncthreads();

  int pp = t >> 7;                  // relation within block
  int d0 = (t & 127) * 4;           // 4 dims per thread (all within one head)
  int h = d0 >> 6;                  // head of these dims
  int rr = blockIdx.x * 2 + pp;
  float m1 = ms[2 * pp][h][0], s1 = ms[2 * pp][h][1];
  float m2 = ms[2 * pp + 1][h][0], s2 = ms[2 * pp + 1][h][1];
  float M = fmaxf(m1, m2);
  float c1 = (m1 == M) ? 1.0f : __expf(m1 - M);
  float c2 = (m2 == M) ? 1.0f : __expf(m2 - M);
  float S = s1 * c1 + s2 * c2;
  float inv = 1.0f / (S + 1e-16f);
  float o0 = (red[2 * pp][d0]     * c1 + red[2 * pp + 1][d0]     * c2) * inv;
  float o1 = (red[2 * pp][d0 + 1] * c1 + red[2 * pp + 1][d0 + 1] * c2) * inv;
  float o2 = (red[2 * pp][d0 + 2] * c1 + red[2 * pp + 1][d0 + 2] * c2) * inv;
  float o3 = (red[2 * pp][d0 + 3] * c1 + red[2 * pp + 1][d0 + 3] * c2) * inv;
  if (flags[0]) {
    uint2 val;
    val.x = (unsigned int)f2b_rne(o0) | ((unsigned int)f2b_rne(o1) << 16);
    val.y = (unsigned int)f2b_rne(o2) | ((unsigned int)f2b_rne(o3) << 16);
    *(uint2*)(outb + (size_t)rr * DIM + d0) = val;
  } else {
    float4 val = { o0, o1, o2, o3 };
    *(float4*)(outf + (size_t)rr * DIM + d0) = val;
  }
}

extern "C" void kernel_launch(void* const* d_in, const int* in_sizes, int n_in,
                              void* d_out, int out_size, void* d_ws, size_t ws_size,
                              hipStream_t stream) {
  ushort_t* canon = (ushort_t*)d_ws;
  ushort_t* c_rel   = canon;
  ushort_t* c_bin   = c_rel + REL_N;
  ushort_t* c_wattn = c_bin + BIN_N;
  ushort_t* c_battn = c_wattn + WATTN_N;
  ushort_t* c_avec  = c_battn + VEC_N;
  ushort_t* c_waggr = c_avec + VEC_N;
  ushort_t* c_baggr = c_waggr + WAGGR_N;
  ushort_t* c_end   = c_baggr + VEC_N;

  int* trip32 = (int*)c_end;
  int* flags  = trip32 + 3 * NEDGE;
  float* P1 = (float*)(flags + 4);
  float* P2 = P1 + NREL * DIM;
  float* P3 = P2 + NBIN * DIM;
  ushort_t* Mw = (ushort_t*)(P3 + NREL * DIM);
  int* cnt  = (int*)(Mw + NREL * DIM);
  int* cur  = cnt + NREL;
  int* off  = cur + NREL;
  unsigned int* etb = (unsigned int*)(off + NREL + 1);

  hipMemsetAsync(cnt, 0, 2 * NREL * sizeof(int), stream);  // cnt + cur

  detect_k<<<1, 256, 0, stream>>>((const ushort_t*)d_in[0], (const int*)d_in[2], flags);

  const int TOT = REL_N + BIN_N + WATTN_N + 3 * VEC_N + WAGGR_N;
  conv_all<<<(TOT + 255) / 256, 256, 0, stream>>>(d_in[0], d_in[1], d_in[3], d_in[4],
                                                  d_in[5], d_in[6], d_in[7], canon, flags);
  convt_count<<<(NEDGE + 255) / 256, 256, 0, stream>>>((const int*)d_in[2], trip32, cnt, flags);
  scan_k<<<1, 256, 0, stream>>>(cnt, off);
  scatter_k<<<(NEDGE + 255) / 256, 256, 0, stream>>>(trip32, off, cur, etb);

  dim3 gg((NREL + 63) / 64, DIM / 64, 4);
  gemm_all<<<gg, 256, 0, stream>>>(c_rel, c_bin, c_wattn, c_battn, c_waggr, c_baggr,
                                   P1, P2, P3, Mw);

  aggr2_k<<<NREL / 2, 256, 0, stream>>>(off, etb, P1, P2, P3, Mw, c_avec,
                                        (float*)d_out, (ushort_t*)d_out, flags);
}

// Round 7
// 174.600 us; speedup vs baseline: 1.4755x; 1.4755x over previous
//
#include <hip/hip_runtime.h>
#include <hip/hip_bf16.h>

#define NREL 5000
#define NBIN 32
#define NEDGE 200000
#define DIM 512
#define NHEAD 8
#define PXLD 1536

typedef __attribute__((ext_vector_type(8))) short short8;
typedef __attribute__((ext_vector_type(4))) float f32x4;
typedef unsigned short ushort_t;

#define REL_N (NREL * DIM)
#define BIN_N (NBIN * DIM)
#define WATTN_N (DIM * 3 * DIM)
#define VEC_N DIM
#define WAGGR_N (DIM * DIM)

__device__ __forceinline__ float b2f(ushort_t u) {
  unsigned int v = ((unsigned int)u) << 16;
  union { unsigned int i; float f; } c; c.i = v; return c.f;
}
__device__ __forceinline__ ushort_t f2b_rne(float f) {
  union { float f; unsigned int u; } c; c.f = f;
  unsigned int u = c.u;
  return (ushort_t)((u + 0x7FFFu + ((u >> 16) & 1u)) >> 16);
}

// ---------- dtype detection ----------
__global__ void detect_k(const ushort_t* __restrict__ emb_raw,
                         const int* __restrict__ trip_raw,
                         int* __restrict__ flags) {
  __shared__ int cnt_s, nz_s;
  if (threadIdx.x == 0) { cnt_s = 0; nz_s = 0; }
  __syncthreads();
  int plaus = 0;
  for (int i = threadIdx.x; i < 4096; i += 256) {
    ushort_t u = emb_raw[2 * i];
    int e = (u >> 7) & 0xFF;
    if (e >= 96 && e <= 159) plaus++;
  }
  atomicAdd(&cnt_s, plaus);
  int nz = 0;
  for (int i = threadIdx.x; i < 2048; i += 256) {
    if (trip_raw[2 * i + 1] != 0) nz++;
  }
  atomicAdd(&nz_s, nz);
  __syncthreads();
  if (threadIdx.x == 0) {
    flags[0] = (cnt_s >= 3900) ? 1 : 0;
    flags[1] = (nz_s == 0) ? 1 : 0;
  }
}

// ---------- canonicalize all float tensors -> bf16 (one kernel) ----------
__global__ void conv_all(const void* __restrict__ s_rel, const void* __restrict__ s_bin,
                         const void* __restrict__ s_wattn, const void* __restrict__ s_battn,
                         const void* __restrict__ s_avec, const void* __restrict__ s_waggr,
                         const void* __restrict__ s_baggr, ushort_t* __restrict__ dst,
                         const int* __restrict__ flags) {
  const int O1 = REL_N, O2 = O1 + BIN_N, O3 = O2 + WATTN_N, O4 = O3 + VEC_N,
            O5 = O4 + VEC_N, O6 = O5 + WAGGR_N, O7 = O6 + VEC_N;
  int i = blockIdx.x * 256 + threadIdx.x;
  if (i >= O7) return;
  const void* src; int j;
  if (i < O1)      { src = s_rel;   j = i; }
  else if (i < O2) { src = s_bin;   j = i - O1; }
  else if (i < O3) { src = s_wattn; j = i - O2; }
  else if (i < O4) { src = s_battn; j = i - O3; }
  else if (i < O5) { src = s_avec;  j = i - O4; }
  else if (i < O6) { src = s_waggr; j = i - O5; }
  else             { src = s_baggr; j = i - O6; }
  dst[i] = flags[0] ? ((const ushort_t*)src)[j] : f2b_rne(((const float*)src)[j]);
}

// ---------- triplets -> int32 (clamped) + head count ----------
__global__ void convt_count(const int* __restrict__ src, int* __restrict__ dst,
                            int* __restrict__ cnt, const int* __restrict__ flags) {
  int e = blockIdx.x * blockDim.x + threadIdx.x;
  if (e >= NEDGE) return;
  int h, ta, bi;
  if (flags[1]) { h = src[6 * e]; ta = src[6 * e + 2]; bi = src[6 * e + 4]; }
  else          { h = src[3 * e]; ta = src[3 * e + 1]; bi = src[3 * e + 2]; }
  h  = min(max(h, 0), NREL - 1);
  ta = min(max(ta, 0), NREL - 1);
  bi = min(max(bi, 0), NBIN - 1);
  dst[3 * e] = h; dst[3 * e + 1] = ta; dst[3 * e + 2] = bi;
  atomicAdd(&cnt[h], 1);
}

// ---------- fast single-block exclusive scan over 5000 counts ----------
__global__ __launch_bounds__(256) void scan_k(const int* __restrict__ cnt, int* __restrict__ off) {
  __shared__ int wsum[4];
  int t = threadIdx.x, l = t & 63, w = t >> 6;
  int base = t * 20;
  int vals[20];
  int s = 0;
#pragma unroll
  for (int j = 0; j < 20; ++j) {
    int v = (base + j < NREL) ? cnt[base + j] : 0;
    vals[j] = s; s += v;
  }
  int x = s;
#pragma unroll
  for (int d = 1; d < 64; d <<= 1) {
    int y = __shfl_up(x, d, 64);
    if (l >= d) x += y;
  }
  if (l == 63) wsum[w] = x;
  __syncthreads();
  int woff = 0;
  for (int k = 0; k < 4; ++k) if (k < w) woff += wsum[k];
  int thr_excl = woff + x - s;
#pragma unroll
  for (int j = 0; j < 20; ++j)
    if (base + j < NREL) off[base + j] = thr_excl + vals[j];
  if (t == 255) off[NREL] = woff + x;
}

// ---------- scatter packed (tail | bin<<16) into CSR slots ----------
__global__ void scatter_k(const int* __restrict__ trip, const int* __restrict__ off,
                          int* __restrict__ cur, unsigned int* __restrict__ etb) {
  int e = blockIdx.x * blockDim.x + threadIdx.x;
  if (e >= NEDGE) return;
  int h = trip[3 * e];
  int ta = trip[3 * e + 1];
  int bi = trip[3 * e + 2];
  int p = atomicAdd(&cur[h], 1);
  etb[off[h] + p] = (unsigned int)ta | ((unsigned int)bi << 16);
}

// ---------- single fused GEMM -> PX[5000][1536] = (P1 | P3 | Mw+b_aggr), bf16
//            corner blocks bx==40 (by<4) -> P2[32][512] = emb_bin.W2^T + b_attn, bf16
__global__ __launch_bounds__(256) void gemm_fused(
    const ushort_t* __restrict__ c_rel, const ushort_t* __restrict__ c_bin,
    const ushort_t* __restrict__ c_wattn, const ushort_t* __restrict__ c_battn,
    const ushort_t* __restrict__ c_waggr, const ushort_t* __restrict__ c_baggr,
    ushort_t* __restrict__ PX, ushort_t* __restrict__ P2)
{
  int bx = blockIdx.x, by = blockIdx.y;
  const ushort_t* A; int Arows;
  const ushort_t* Bbase; int Bld; int joff;
  const ushort_t* bias;
  ushort_t* OUT; int OUTld;
  int rbase;
  if (bx == 40) {
    if (by >= 4) return;
    A = c_bin; Arows = NBIN; rbase = 0;          // P2 rows start at 0!
    Bbase = c_wattn + 512; Bld = 3 * DIM; joff = 0;
    bias = c_battn;
    OUT = P2; OUTld = DIM;
  } else {
    A = c_rel; Arows = NREL; rbase = bx * 128;
    int seg = by >> 2;
    if (seg == 2)      { Bbase = c_waggr;        Bld = DIM;     bias = c_baggr; }
    else if (seg == 1) { Bbase = c_wattn + 1024; Bld = 3 * DIM; bias = nullptr; }
    else               { Bbase = c_wattn;        Bld = 3 * DIM; bias = nullptr; }
    joff = seg * 512;
    OUT = PX; OUTld = PXLD;
  }
  int l = threadIdx.x & 63, wv = threadIdx.x >> 6;
  int wr = wv >> 1, wc = wv & 1;
  int rt = rbase + wr * 64;
  int ct = by * 128 + wc * 64;
  int klo = (l >> 4) * 8;
  int rA = rt + (l & 15);
  f32x4 acc[4][4] = {};
  for (int kk = 0; kk < DIM; kk += 32) {
    short8 aF[4], bF[4];
#pragma unroll
    for (int m2 = 0; m2 < 4; ++m2) {
      int row = rA + m2 * 16;
      aF[m2] = (row < Arows) ? *(const short8*)(A + (size_t)row * DIM + kk + klo)
                             : (short8){0,0,0,0,0,0,0,0};
    }
#pragma unroll
    for (int n = 0; n < 4; ++n) {
      int j = ct + n * 16 + (l & 15) - joff;
      bF[n] = *(const short8*)(Bbase + (size_t)j * Bld + kk + klo);
    }
#pragma unroll
    for (int m2 = 0; m2 < 4; ++m2)
#pragma unroll
      for (int n = 0; n < 4; ++n)
        acc[m2][n] = __builtin_amdgcn_mfma_f32_16x16x32_bf16(aF[m2], bF[n], acc[m2][n], 0, 0, 0);
  }
  int r0 = rt + (l >> 4) * 4;
#pragma unroll
  for (int n = 0; n < 4; ++n) {
    int col = ct + n * 16 + (l & 15);
    float bv = bias ? b2f(bias[col - joff]) : 0.0f;
#pragma unroll
    for (int m2 = 0; m2 < 4; ++m2) {
#pragma unroll
      for (int jj = 0; jj < 4; ++jj) {
        int row = r0 + m2 * 16 + jj;
        if (row < Arows) OUT[(size_t)row * OUTld + col] = f2b_rne(acc[m2][n][jj] + bv);
      }
    }
  }
}

// ---------- aggregation: 2 waves per relation, 2 relations per block ----------
// single-pass online softmax (per head) with defer-max; barrier-free main loop
__global__ __launch_bounds__(256, 8) void aggr2_k(
    const int* __restrict__ off, const unsigned int* __restrict__ etb,
    const ushort_t* __restrict__ PX, const ushort_t* __restrict__ P2,
    const ushort_t* __restrict__ avec, float* __restrict__ outf,
    ushort_t* __restrict__ outb, const int* __restrict__ flags)
{
  __shared__ __align__(16) float red[4][DIM];
  __shared__ float ms[4][NHEAD][2];   // per-wave, per-head (m, s)

  int t = threadIdx.x;
  int l = t & 63, wv = t >> 6;
  int p = wv >> 1, sub = wv & 1;
  int r = blockIdx.x * 2 + p;
  int off0 = off[r];
  int nE = off[r + 1] - off0;
  int half = nE >> 1;
  int start = sub ? half : 0;
  int cnt = sub ? (nE - half) : half;

  int hd1 = l >> 3;                 // head owned by this 8-lane group
  int ob = hd1 * 64 + (l & 7) * 8;  // dim block for the logit dot

  float p1v[8], avv[8];
  {
    short8 p1b = *(const short8*)(PX + (size_t)r * PXLD + ob);
#pragma unroll
    for (int j = 0; j < 8; ++j) {
      p1v[j] = b2f((ushort_t)p1b[j]);
      avv[j] = b2f(avec[ob + j]);
    }
  }
  float acc[8] = {};
  float m = -INFINITY, s = 0.0f;

  for (int ck = 0; ck < cnt; ck += 64) {
    int ne = min(64, cnt - ck);
    unsigned int tbreg = 0;
    if (l < ne) tbreg = etb[off0 + start + ck + l];
    for (int i = 0; i < ne; ++i) {
      unsigned int tb = __shfl((int)tbreg, i);
      int tail = tb & 0xFFFF;
      int bin = tb >> 16;
      short8 p2v = *(const short8*)(P2 + bin * DIM + ob);
      short8 p3v = *(const short8*)(PX + (size_t)tail * PXLD + 512 + ob);
      short8 mv  = *(const short8*)(PX + (size_t)tail * PXLD + 1024 + 8 * l);
      float part = 0.0f;
#pragma unroll
      for (int j = 0; j < 8; ++j) {
        float z = p1v[j] + b2f((ushort_t)p2v[j]) + b2f((ushort_t)p3v[j]);
        z = z > 0.f ? z : 0.2f * z;
        part += z * avv[j];
      }
      part += __shfl_xor(part, 1);
      part += __shfl_xor(part, 2);
      part += __shfl_xor(part, 4);   // per-head logit (uniform within 8-lane group)
      if (part > m + 8.0f) {         // defer-max rescale (group-uniform branch)
        float f = __expf(m - part);  // first edge: exp(-inf)=0
        s *= f;
#pragma unroll
        for (int j = 0; j < 8; ++j) acc[j] *= f;
        m = part;
      }
      float ev = __expf(part - m);
      s += ev;
#pragma unroll
      for (int j = 0; j < 8; ++j) acc[j] += ev * b2f((ushort_t)mv[j]);
    }
  }

  // ---- merge the two half-relation waves (one barrier) ----
#pragma unroll
  for (int j = 0; j < 8; ++j) red[wv][8 * l + j] = acc[j];
  if ((l & 7) == 0) { ms[wv][hd1][0] = m; ms[wv][hd1][1] = s; }
  __syncthreads();

  int pp = t >> 7;                  // relation within block
  int d0 = (t & 127) * 4;           // 4 dims per thread (within one head)
  int h = d0 >> 6;                  // head of these dims
  int rr = blockIdx.x * 2 + pp;
  float m1 = ms[2 * pp][h][0], s1 = ms[2 * pp][h][1];
  float m2 = ms[2 * pp + 1][h][0], s2 = ms[2 * pp + 1][h][1];
  float M = fmaxf(m1, m2);
  float c1 = (m1 == M) ? 1.0f : __expf(m1 - M);
  float c2 = (m2 == M) ? 1.0f : __expf(m2 - M);
  float S = s1 * c1 + s2 * c2;
  float inv = 1.0f / (S + 1e-16f);
  float o0 = (red[2 * pp][d0]     * c1 + red[2 * pp + 1][d0]     * c2) * inv;
  float o1 = (red[2 * pp][d0 + 1] * c1 + red[2 * pp + 1][d0 + 1] * c2) * inv;
  float o2 = (red[2 * pp][d0 + 2] * c1 + red[2 * pp + 1][d0 + 2] * c2) * inv;
  float o3 = (red[2 * pp][d0 + 3] * c1 + red[2 * pp + 1][d0 + 3] * c2) * inv;
  if (flags[0]) {
    uint2 val;
    val.x = (unsigned int)f2b_rne(o0) | ((unsigned int)f2b_rne(o1) << 16);
    val.y = (unsigned int)f2b_rne(o2) | ((unsigned int)f2b_rne(o3) << 16);
    *(uint2*)(outb + (size_t)rr * DIM + d0) = val;
  } else {
    float4 val = { o0, o1, o2, o3 };
    *(float4*)(outf + (size_t)rr * DIM + d0) = val;
  }
}

extern "C" void kernel_launch(void* const* d_in, const int* in_sizes, int n_in,
                              void* d_out, int out_size, void* d_ws, size_t ws_size,
                              hipStream_t stream) {
  ushort_t* canon = (ushort_t*)d_ws;
  ushort_t* c_rel   = canon;
  ushort_t* c_bin   = c_rel + REL_N;
  ushort_t* c_wattn = c_bin + BIN_N;
  ushort_t* c_battn = c_wattn + WATTN_N;
  ushort_t* c_avec  = c_battn + VEC_N;
  ushort_t* c_waggr = c_avec + VEC_N;
  ushort_t* c_baggr = c_waggr + WAGGR_N;
  ushort_t* c_end   = c_baggr + VEC_N;

  int* trip32 = (int*)c_end;
  int* flags  = trip32 + 3 * NEDGE;
  ushort_t* PX = (ushort_t*)(flags + 4);     // 5000*1536 bf16
  ushort_t* P2 = PX + (size_t)NREL * PXLD;   // 32*512 bf16
  int* cnt  = (int*)(P2 + NBIN * DIM);
  int* cur  = cnt + NREL;
  int* off  = cur + NREL;
  unsigned int* etb = (unsigned int*)(off + NREL + 1);

  hipMemsetAsync(cnt, 0, 2 * NREL * sizeof(int), stream);  // cnt + cur

  detect_k<<<1, 256, 0, stream>>>((const ushort_t*)d_in[0], (const int*)d_in[2], flags);

  const int TOT = REL_N + BIN_N + WATTN_N + 3 * VEC_N + WAGGR_N;
  conv_all<<<(TOT + 255) / 256, 256, 0, stream>>>(d_in[0], d_in[1], d_in[3], d_in[4],
                                                  d_in[5], d_in[6], d_in[7], canon, flags);
  convt_count<<<(NEDGE + 255) / 256, 256, 0, stream>>>((const int*)d_in[2], trip32, cnt, flags);
  scan_k<<<1, 256, 0, stream>>>(cnt, off);
  scatter_k<<<(NEDGE + 255) / 256, 256, 0, stream>>>(trip32, off, cur, etb);

  dim3 gg(41, 12);
  gemm_fused<<<gg, 256, 0, stream>>>(c_rel, c_bin, c_wattn, c_battn, c_waggr, c_baggr,
                                     PX, P2);

  aggr2_k<<<NREL / 2, 256, 0, stream>>>(off, etb, PX, P2, c_avec,
                                        (float*)d_out, (ushort_t*)d_out, flags);
}

// Round 12
// 156.113 us; speedup vs baseline: 1.6502x; 1.1184x over previous
//
#include <hip/hip_runtime.h>
#include <hip/hip_bf16.h>

#define NREL 5000
#define NBIN 32
#define NEDGE 200000
#define DIM 512
#define NHEAD 8
#define PXLD 1536

typedef __attribute__((ext_vector_type(8))) short short8;
typedef __attribute__((ext_vector_type(4))) short short4v;
typedef __attribute__((ext_vector_type(4))) float f32x4;
typedef unsigned short ushort_t;

#define REL_N (NREL * DIM)
#define BIN_N (NBIN * DIM)
#define WATTN_N (DIM * 3 * DIM)
#define WAGGR_N (DIM * DIM)

__device__ __forceinline__ float b2f(ushort_t u) {
  unsigned int v = ((unsigned int)u) << 16;
  union { unsigned int i; float f; } c; c.i = v; return c.f;
}
__device__ __forceinline__ ushort_t f2b_rne(float f) {
  union { float f; unsigned int u; } c; c.f = f;
  unsigned int u = c.u;
  return (ushort_t)((u + 0x7FFFu + ((u >> 16) & 1u)) >> 16);
}

// ---------- convert the 4 MFMA-input tensors f32 -> bf16 (float4-vectorized) ----------
__global__ void conv_all(const float* __restrict__ s_rel, const float* __restrict__ s_bin,
                         const float* __restrict__ s_wattn, const float* __restrict__ s_waggr,
                         ushort_t* __restrict__ dst) {
  const int O1 = REL_N, O2 = O1 + BIN_N, O3 = O2 + WATTN_N, O4 = O3 + WAGGR_N;
  int i4 = (blockIdx.x * 256 + threadIdx.x) * 4;
  if (i4 >= O4) return;
  const float* src; int j;
  if (i4 < O1)      { src = s_rel;   j = i4; }
  else if (i4 < O2) { src = s_bin;   j = i4 - O1; }
  else if (i4 < O3) { src = s_wattn; j = i4 - O2; }
  else              { src = s_waggr; j = i4 - O3; }
  float4 v = *(const float4*)(src + j);
  short4v o;
  o[0] = (short)f2b_rne(v.x); o[1] = (short)f2b_rne(v.y);
  o[2] = (short)f2b_rne(v.z); o[3] = (short)f2b_rne(v.w);
  *(short4v*)(dst + i4) = o;
}

// ---------- head count (int32 triplets) ----------
__global__ void count_k(const int* __restrict__ src, int* __restrict__ cnt) {
  int e = blockIdx.x * 256 + threadIdx.x;
  if (e >= NEDGE) return;
  int h = src[3 * e];
  h = min(max(h, 0), NREL - 1);
  atomicAdd(&cnt[h], 1);
}

// ---------- fast single-block exclusive scan over 5000 counts ----------
__global__ __launch_bounds__(256) void scan_k(const int* __restrict__ cnt, int* __restrict__ off) {
  __shared__ int wsum[4];
  int t = threadIdx.x, l = t & 63, w = t >> 6;
  int base = t * 20;
  int vals[20];
  int s = 0;
#pragma unroll
  for (int j = 0; j < 20; ++j) {
    int v = (base + j < NREL) ? cnt[base + j] : 0;
    vals[j] = s; s += v;
  }
  int x = s;
#pragma unroll
  for (int d = 1; d < 64; d <<= 1) {
    int y = __shfl_up(x, d, 64);
    if (l >= d) x += y;
  }
  if (l == 63) wsum[w] = x;
  __syncthreads();
  int woff = 0;
  for (int k = 0; k < 4; ++k) if (k < w) woff += wsum[k];
  int thr_excl = woff + x - s;
#pragma unroll
  for (int j = 0; j < 20; ++j)
    if (base + j < NREL) off[base + j] = thr_excl + vals[j];
  if (t == 255) off[NREL] = woff + x;
}

// ---------- scatter packed (tail | bin<<16) into CSR slots (int32 triplets) ----------
__global__ void scatter_k(const int* __restrict__ src, const int* __restrict__ off,
                          int* __restrict__ cur, unsigned int* __restrict__ etb) {
  int e = blockIdx.x * 256 + threadIdx.x;
  if (e >= NEDGE) return;
  int h  = src[3 * e];
  int ta = src[3 * e + 1];
  int bi = src[3 * e + 2];
  h  = min(max(h, 0), NREL - 1);
  ta = min(max(ta, 0), NREL - 1);
  bi = min(max(bi, 0), NBIN - 1);
  int p = atomicAdd(&cur[h], 1);
  etb[off[h] + p] = (unsigned int)ta | ((unsigned int)bi << 16);
}

// ---------- LDS-staged (via registers) fused GEMM
//   PX[5000][1536] = (P1 | P3 | Mw+b_aggr), bf16
//   corner blocks bx==40 (by<4) -> P2[32][512] = emb_bin.W2^T + b_attn
__global__ __launch_bounds__(256) void gemm_fused(
    const ushort_t* __restrict__ c_rel, const ushort_t* __restrict__ c_bin,
    const ushort_t* __restrict__ c_wattn, const float* __restrict__ b_attn,
    const ushort_t* __restrict__ c_waggr, const float* __restrict__ b_aggr,
    ushort_t* __restrict__ PX, ushort_t* __restrict__ P2)
{
  __shared__ ushort_t Alds[128 * 32];
  __shared__ ushort_t Blds[128 * 32];
  int bx = blockIdx.x, by = blockIdx.y;
  const ushort_t* A; int Arows;
  const ushort_t* Bbase; int Bld; int joff;
  const float* bias;
  ushort_t* OUT; int OUTld;
  int rbase;
  if (bx == 40) {
    if (by >= 4) return;
    A = c_bin; Arows = NBIN; rbase = 0;
    Bbase = c_wattn + 512; Bld = 3 * DIM; joff = 0;
    bias = b_attn;
    OUT = P2; OUTld = DIM;
  } else {
    A = c_rel; Arows = NREL; rbase = bx * 128;
    int seg = by >> 2;
    if (seg == 2)      { Bbase = c_waggr;        Bld = DIM;     bias = b_aggr; }
    else if (seg == 1) { Bbase = c_wattn + 1024; Bld = 3 * DIM; bias = nullptr; }
    else               { Bbase = c_wattn;        Bld = 3 * DIM; bias = nullptr; }
    joff = seg * 512;
    OUT = PX; OUTld = PXLD;
  }
  int l = threadIdx.x & 63, wv = threadIdx.x >> 6;
  int wr = wv >> 1, wc = wv & 1;
  int ctb = by * 128;
  int r16 = l >> 2, sub = l & 3;        // staging: lane -> (row within 16-row chunk, 16B sub)
  int klo = (l >> 4) * 8;
  // per-wave staging chunks (2 for A, 2 for B), each = 16 rows x 32 K-elems = 1 KB
  int ia0 = wv * 2, ia1 = wv * 2 + 1;
  int arow0 = min(rbase + ia0 * 16 + r16, Arows - 1);
  int arow1 = min(rbase + ia1 * 16 + r16, Arows - 1);
  int jloc0 = ctb + ia0 * 16 + r16 - joff;
  int jloc1 = ctb + ia1 * 16 + r16 - joff;
  const ushort_t* aSrc0 = A + (size_t)arow0 * DIM + sub * 8;
  const ushort_t* aSrc1 = A + (size_t)arow1 * DIM + sub * 8;
  const ushort_t* bSrc0 = Bbase + (size_t)jloc0 * Bld + sub * 8;
  const ushort_t* bSrc1 = Bbase + (size_t)jloc1 * Bld + sub * 8;
  // explicit per-lane LDS write addresses: chunk base + l*16B
  ushort_t* aDst0 = Alds + ia0 * 512 + l * 8;
  ushort_t* aDst1 = Alds + ia1 * 512 + l * 8;
  ushort_t* bDst0 = Blds + ia0 * 512 + l * 8;
  ushort_t* bDst1 = Blds + ia1 * 512 + l * 8;

  f32x4 acc[4][4] = {};
  for (int kk = 0; kk < DIM; kk += 32) {
    short8 sa0 = *(const short8*)(aSrc0 + kk);
    short8 sa1 = *(const short8*)(aSrc1 + kk);
    short8 sb0 = *(const short8*)(bSrc0 + kk);
    short8 sb1 = *(const short8*)(bSrc1 + kk);
    if (kk) __syncthreads();            // prev iter's ds_reads done before overwrite
    *(short8*)aDst0 = sa0;
    *(short8*)aDst1 = sa1;
    *(short8*)bDst0 = sb0;
    *(short8*)bDst1 = sb1;
    __syncthreads();                    // staging visible to all waves
    short8 aF[4], bF[4];
#pragma unroll
    for (int m2 = 0; m2 < 4; ++m2)
      aF[m2] = *(const short8*)(Alds + (wr * 64 + m2 * 16 + (l & 15)) * 32 + klo);
#pragma unroll
    for (int n = 0; n < 4; ++n)
      bF[n] = *(const short8*)(Blds + (wc * 64 + n * 16 + (l & 15)) * 32 + klo);
#pragma unroll
    for (int m2 = 0; m2 < 4; ++m2)
#pragma unroll
      for (int n = 0; n < 4; ++n)
        acc[m2][n] = __builtin_amdgcn_mfma_f32_16x16x32_bf16(aF[m2], bF[n], acc[m2][n], 0, 0, 0);
  }
  int r0 = rbase + wr * 64 + (l >> 4) * 4;
#pragma unroll
  for (int n = 0; n < 4; ++n) {
    int col = ctb + wc * 64 + n * 16 + (l & 15);
    float bv = bias ? bias[col - joff] : 0.0f;
#pragma unroll
    for (int m2 = 0; m2 < 4; ++m2) {
#pragma unroll
      for (int jj = 0; jj < 4; ++jj) {
        int row = r0 + m2 * 16 + jj;
        if (row < Arows) OUT[(size_t)row * OUTld + col] = f2b_rne(acc[m2][n][jj] + bv);
      }
    }
  }
}

// ---------- aggregation: 2 waves per relation, 2 relations per block ----------
// single-pass per-head online softmax with defer-max (round-7 proven loop); f32 out
__global__ __launch_bounds__(256, 8) void aggr2_k(
    const int* __restrict__ off, const unsigned int* __restrict__ etb,
    const ushort_t* __restrict__ PX, const ushort_t* __restrict__ P2,
    const float* __restrict__ avec, float* __restrict__ outf)
{
  __shared__ __align__(16) float red[4][DIM];
  __shared__ float ms[4][NHEAD][2];   // per-wave, per-head (m, s)

  int t = threadIdx.x;
  int l = t & 63, wv = t >> 6;
  int p = wv >> 1, sub = wv & 1;
  int r = blockIdx.x * 2 + p;
  int off0 = off[r];
  int nE = off[r + 1] - off0;
  int half = nE >> 1;
  int start = sub ? half : 0;
  int cnt = sub ? (nE - half) : half;

  int hd1 = l >> 3;                 // head owned by this 8-lane group
  int ob = hd1 * 64 + (l & 7) * 8;  // dim block for the logit dot

  float p1v[8], avv[8];
  {
    short8 p1b = *(const short8*)(PX + (size_t)r * PXLD + ob);
#pragma unroll
    for (int j = 0; j < 8; ++j) {
      p1v[j] = b2f((ushort_t)p1b[j]);
      avv[j] = avec[ob + j];
    }
  }
  float acc[8] = {};
  float m = -INFINITY, s = 0.0f;

  for (int ck = 0; ck < cnt; ck += 64) {
    int ne = min(64, cnt - ck);
    unsigned int tbreg = 0;
    if (l < ne) tbreg = etb[off0 + start + ck + l];
    for (int i = 0; i < ne; ++i) {
      unsigned int tb = __shfl((int)tbreg, i);
      int tail = tb & 0xFFFF;
      int bin = tb >> 16;
      short8 p2v = *(const short8*)(P2 + bin * DIM + ob);
      short8 p3v = *(const short8*)(PX + (size_t)tail * PXLD + 512 + ob);
      short8 mv  = *(const short8*)(PX + (size_t)tail * PXLD + 1024 + 8 * l);
      float part = 0.0f;
#pragma unroll
      for (int j = 0; j < 8; ++j) {
        float z = p1v[j] + b2f((ushort_t)p2v[j]) + b2f((ushort_t)p3v[j]);
        z = z > 0.f ? z : 0.2f * z;
        part += z * avv[j];
      }
      part += __shfl_xor(part, 1);
      part += __shfl_xor(part, 2);
      part += __shfl_xor(part, 4);   // per-head logit (uniform within 8-lane group)
      if (part > m + 8.0f) {         // defer-max rescale (group-uniform branch)
        float f = __expf(m - part);  // first edge: exp(-inf)=0
        s *= f;
#pragma unroll
        for (int j = 0; j < 8; ++j) acc[j] *= f;
        m = part;
      }
      float ev = __expf(part - m);
      s += ev;
#pragma unroll
      for (int j = 0; j < 8; ++j) acc[j] += ev * b2f((ushort_t)mv[j]);
    }
  }

  // ---- merge the two half-relation waves (one barrier) ----
#pragma unroll
  for (int j = 0; j < 8; ++j) red[wv][8 * l + j] = acc[j];
  if ((l & 7) == 0) { ms[wv][hd1][0] = m; ms[wv][hd1][1] = s; }
  __syncthreads();

  int pp = t >> 7;                  // relation within block
  int d0 = (t & 127) * 4;           // 4 dims per thread (within one head)
  int h = d0 >> 6;                  // head of these dims
  int rr = blockIdx.x * 2 + pp;
  float m1 = ms[2 * pp][h][0], s1 = ms[2 * pp][h][1];
  float m2 = ms[2 * pp + 1][h][0], s2 = ms[2 * pp + 1][h][1];
  float M = fmaxf(m1, m2);
  float c1 = (m1 == M) ? 1.0f : __expf(m1 - M);
  float c2 = (m2 == M) ? 1.0f : __expf(m2 - M);
  float S = s1 * c1 + s2 * c2;
  float inv = 1.0f / (S + 1e-16f);
  float4 val;
  val.x = (red[2 * pp][d0]     * c1 + red[2 * pp + 1][d0]     * c2) * inv;
  val.y = (red[2 * pp][d0 + 1] * c1 + red[2 * pp + 1][d0 + 1] * c2) * inv;
  val.z = (red[2 * pp][d0 + 2] * c1 + red[2 * pp + 1][d0 + 2] * c2) * inv;
  val.w = (red[2 * pp][d0 + 3] * c1 + red[2 * pp + 1][d0 + 3] * c2) * inv;
  *(float4*)(outf + (size_t)rr * DIM + d0) = val;
}

extern "C" void kernel_launch(void* const* d_in, const int* in_sizes, int n_in,
                              void* d_out, int out_size, void* d_ws, size_t ws_size,
                              hipStream_t stream) {
  const float* s_rel   = (const float*)d_in[0];
  const float* s_bin   = (const float*)d_in[1];
  const int*   trip    = (const int*)d_in[2];     // int32 (JAX x64 off folds int64->int32)
  const float* s_wattn = (const float*)d_in[3];
  const float* b_attn  = (const float*)d_in[4];
  const float* avec    = (const float*)d_in[5];
  const float* s_waggr = (const float*)d_in[6];
  const float* b_aggr  = (const float*)d_in[7];

  ushort_t* canon = (ushort_t*)d_ws;
  ushort_t* c_rel   = canon;
  ushort_t* c_bin   = c_rel + REL_N;
  ushort_t* c_wattn = c_bin + BIN_N;
  ushort_t* c_waggr = c_wattn + WATTN_N;
  int* cnt = (int*)(c_waggr + WAGGR_N);
  int* cur = cnt + NREL;
  int* off = cur + NREL;                          // NREL+1
  unsigned int* etb = (unsigned int*)(off + NREL + 1);
  ushort_t* PX = (ushort_t*)(((uintptr_t)(etb + NEDGE) + 15) & ~(uintptr_t)15);
  ushort_t* P2 = PX + (size_t)NREL * PXLD;

  hipMemsetAsync(cnt, 0, 2 * NREL * sizeof(int), stream);  // cnt + cur

  const int CTOT = REL_N + BIN_N + WATTN_N + WAGGR_N;      // all div by 4
  conv_all<<<(CTOT / 4 + 255) / 256, 256, 0, stream>>>(s_rel, s_bin, s_wattn, s_waggr, canon);
  count_k<<<(NEDGE + 255) / 256, 256, 0, stream>>>(trip, cnt);
  scan_k<<<1, 256, 0, stream>>>(cnt, off);
  scatter_k<<<(NEDGE + 255) / 256, 256, 0, stream>>>(trip, off, cur, etb);

  dim3 gg(41, 12);
  gemm_fused<<<gg, 256, 0, stream>>>(c_rel, c_bin, c_wattn, b_attn, c_waggr, b_aggr,
                                     PX, P2);

  aggr2_k<<<NREL / 2, 256, 0, stream>>>(off, etb, PX, P2, avec, (float*)d_out);
}